// Round 3
// baseline (392.511 us; speedup 1.0000x reference)
//
#include <hip/hip_runtime.h>
#include <hip/hip_bf16.h>
#include <stdint.h>

#define N_TOK 8192
#define D 128
#define QTILES (N_TOK / 16)  // 512

typedef __attribute__((ext_vector_type(8))) short short8;   // bf16x8 MFMA frag
typedef __attribute__((ext_vector_type(4))) short short4v;  // 4 bf16 (8B store)
typedef __attribute__((ext_vector_type(4))) float f32x4;    // MFMA accum

__device__ __forceinline__ ushort f2bf(float f) {
    union { float f; uint32_t u; } cv; cv.f = f;
    uint32_t u = cv.u;
    return (ushort)((u + 0x7fffu + ((u >> 16) & 1u)) >> 16);  // RNE
}
__device__ __forceinline__ float bf2f(ushort h) {
    union { uint32_t u; float f; } cv; cv.u = ((uint32_t)h) << 16;
    return cv.f;
}
__device__ __forceinline__ f32x4 zero4() {
    f32x4 z; z[0] = 0.f; z[1] = 0.f; z[2] = 0.f; z[3] = 0.f; return z;
}

// -------- kernel 1: f32 -> double-bf16 split (X and the 3 weights) ----------
__global__ void cvt_kernel(const float* __restrict__ X, const float* __restrict__ Wq,
                           const float* __restrict__ Wk, const float* __restrict__ Wv,
                           ushort* __restrict__ Xhi, ushort* __restrict__ Xlo,
                           ushort* __restrict__ Whi, ushort* __restrict__ Wlo, int nX) {
    int i = blockIdx.x * blockDim.x + threadIdx.x;
    int e = i * 4;
    int total = nX + 3 * 16384;
    if (e >= total) return;
    const float* src; ushort* dhi; ushort* dlo; int off;
    if (e < nX) { src = X; dhi = Xhi; dlo = Xlo; off = e; }
    else {
        int w = e - nX;
        int m = w >> 14;
        off = w & 16383;
        src = (m == 0) ? Wq : ((m == 1) ? Wk : Wv);
        dhi = Whi + (m << 14);
        dlo = Wlo + (m << 14);
    }
    f32x4 v = *(const f32x4*)(src + off);
    short4v ph, pl;
    #pragma unroll
    for (int r = 0; r < 4; ++r) {
        ushort h = f2bf(v[r]);
        ph[r] = (short)h;
        pl[r] = (short)f2bf(v[r] - bf2f(h));
    }
    *(short4v*)(dhi + off) = ph;
    *(short4v*)(dlo + off) = pl;
}

// -------- kernel 2: projections via MFMA (double-bf16 inputs) ---------------
__global__ __launch_bounds__(64) void proj_kernel(
    const ushort* __restrict__ Xhi, const ushort* __restrict__ Xlo,
    const ushort* __restrict__ Whi, const ushort* __restrict__ Wlo,
    ushort* __restrict__ Qhi, ushort* __restrict__ Qlo,
    ushort* __restrict__ Khi, ushort* __restrict__ Klo, ushort* __restrict__ Vt) {
    const int lane = threadIdx.x & 63;
    const int g = lane >> 4, r16 = lane & 15;
    const int nbase = blockIdx.x * 16;

    short8 xh[4], xl[4];
    const ushort* xrh = Xhi + (size_t)(nbase + r16) * D + 8 * g;
    const ushort* xrl = Xlo + (size_t)(nbase + r16) * D + 8 * g;
    #pragma unroll
    for (int ds = 0; ds < 4; ++ds) {
        xh[ds] = *(const short8*)(xrh + 32 * ds);
        xl[ds] = *(const short8*)(xrl + 32 * ds);
    }

    #pragma unroll
    for (int m = 0; m < 2; ++m) {
        const ushort* Wh = Whi + m * 16384;
        const ushort* Wl = Wlo + m * 16384;
        ushort* Oh = m ? Khi : Qhi;
        ushort* Ol = m ? Klo : Qlo;
        #pragma unroll
        for (int jt = 0; jt < 8; ++jt) {
            f32x4 acc = zero4();
            const ushort* wrh = Wh + (size_t)(16 * jt + r16) * D + 8 * g;
            const ushort* wrl = Wl + (size_t)(16 * jt + r16) * D + 8 * g;
            #pragma unroll
            for (int ds = 0; ds < 4; ++ds) {
                short8 wh = *(const short8*)(wrh + 32 * ds);
                short8 wl = *(const short8*)(wrl + 32 * ds);
                acc = __builtin_amdgcn_mfma_f32_16x16x32_bf16(wh, xh[ds], acc, 0, 0, 0);
                acc = __builtin_amdgcn_mfma_f32_16x16x32_bf16(wh, xl[ds], acc, 0, 0, 0);
                acc = __builtin_amdgcn_mfma_f32_16x16x32_bf16(wl, xh[ds], acc, 0, 0, 0);
            }
            short4v ph, pl;
            #pragma unroll
            for (int r = 0; r < 4; ++r) {
                ushort h = f2bf(acc[r]);
                ph[r] = (short)h;
                pl[r] = (short)f2bf(acc[r] - bf2f(h));
            }
            size_t oo = (size_t)(nbase + r16) * D + 16 * jt + 4 * g;
            *(short4v*)(Oh + oo) = ph;
            *(short4v*)(Ol + oo) = pl;
        }
    }
    {
        const ushort* Wh = Whi + 32768;
        const ushort* Wl = Wlo + 32768;
        #pragma unroll
        for (int jt = 0; jt < 8; ++jt) {
            f32x4 acc = zero4();
            const ushort* wrh = Wh + (size_t)(16 * jt + r16) * D + 8 * g;
            const ushort* wrl = Wl + (size_t)(16 * jt + r16) * D + 8 * g;
            #pragma unroll
            for (int ds = 0; ds < 4; ++ds) {
                short8 wh = *(const short8*)(wrh + 32 * ds);
                short8 wl = *(const short8*)(wrl + 32 * ds);
                acc = __builtin_amdgcn_mfma_f32_16x16x32_bf16(xh[ds], wh, acc, 0, 0, 0);
                acc = __builtin_amdgcn_mfma_f32_16x16x32_bf16(xl[ds], wh, acc, 0, 0, 0);
                acc = __builtin_amdgcn_mfma_f32_16x16x32_bf16(xh[ds], wl, acc, 0, 0, 0);
            }
            short4v pk;
            #pragma unroll
            for (int r = 0; r < 4; ++r) pk[r] = (short)f2bf(acc[r]);
            *(short4v*)(Vt + (size_t)(16 * jt + r16) * N_TOK + nbase + 4 * g) = pk;
        }
    }
}

// -------- kernel 3: flash attention (split-KV partials) ---------------------
// sp = blockIdx % NS: with NS=8 and round-robin block->XCD mapping, each XCD
// works on exactly one KV split -> split's K/V stays resident in that L2.
template<int NS>
__global__ __launch_bounds__(64, 4) void flash_kernel(
    const ushort* __restrict__ Qhi, const ushort* __restrict__ Qlo,
    const ushort* __restrict__ Khi, const ushort* __restrict__ Klo,
    const ushort* __restrict__ Vt, float* __restrict__ Op, float* __restrict__ ML) {
    __shared__ __align__(16) ushort P_lds[16 * 64];
    const int lane = threadIdx.x & 63;
    const int g = lane >> 4, r16 = lane & 15;
    const int sp = blockIdx.x % NS;
    const int qt = blockIdx.x / NS;
    const int qbase = qt * 16;
    const int kv0 = sp * (N_TOK / NS);
    const int kv1 = kv0 + (N_TOK / NS);
    const int swz = (r16 & 7) << 3;            // XOR swizzle, bank-conflict fix

    short8 qh[4], ql[4];
    const ushort* qrh = Qhi + (size_t)(qbase + r16) * D + 8 * g;
    const ushort* qrl = Qlo + (size_t)(qbase + r16) * D + 8 * g;
    #pragma unroll
    for (int ds = 0; ds < 4; ++ds) {
        qh[ds] = *(const short8*)(qrh + 32 * ds);
        ql[ds] = *(const short8*)(qrl + 32 * ds);
    }

    float m = -INFINITY, l = 0.f;
    f32x4 o[8];
    #pragma unroll
    for (int dt = 0; dt < 8; ++dt) o[dt] = zero4();

    for (int kv = kv0; kv < kv1; kv += 64) {
        // --- S^T = K*Q^T : 4 k-tiles x 4 d-slices x 3 split terms
        f32x4 s[4];
        #pragma unroll
        for (int t = 0; t < 4; ++t) {
            s[t] = zero4();
            const ushort* krh = Khi + (size_t)(kv + 16 * t + r16) * D + 8 * g;
            const ushort* krl = Klo + (size_t)(kv + 16 * t + r16) * D + 8 * g;
            #pragma unroll
            for (int ds = 0; ds < 4; ++ds) {
                short8 kh = *(const short8*)(krh + 32 * ds);
                short8 kl = *(const short8*)(krl + 32 * ds);
                s[t] = __builtin_amdgcn_mfma_f32_16x16x32_bf16(kh, qh[ds], s[t], 0, 0, 0);
                s[t] = __builtin_amdgcn_mfma_f32_16x16x32_bf16(kh, ql[ds], s[t], 0, 0, 0);
                s[t] = __builtin_amdgcn_mfma_f32_16x16x32_bf16(kl, qh[ds], s[t], 0, 0, 0);
            }
        }
        // --- online softmax: lane holds 16 scores of its own q-row
        float tm = -INFINITY;
        #pragma unroll
        for (int t = 0; t < 4; ++t) {
            #pragma unroll
            for (int r = 0; r < 4; ++r) tm = fmaxf(tm, s[t][r]);
        }
        tm = fmaxf(tm, __shfl_xor(tm, 16));
        tm = fmaxf(tm, __shfl_xor(tm, 32));
        float mnew = fmaxf(m, tm);
        float scale = __expf(m - mnew);
        float psum = 0.f;
        ushort pb[16];
        #pragma unroll
        for (int t = 0; t < 4; ++t) {
            #pragma unroll
            for (int r = 0; r < 4; ++r) {
                float p = __expf(s[t][r] - mnew);
                psum += p;
                pb[4 * t + r] = f2bf(p);
            }
        }
        psum += __shfl_xor(psum, 16);
        psum += __shfl_xor(psum, 32);
        l = l * scale + psum;
        m = mnew;
        #pragma unroll
        for (int dt = 0; dt < 8; ++dt) o[dt] *= scale;
        // --- P -> LDS (lane writes 4 consecutive kpos of its q-row, swizzled)
        #pragma unroll
        for (int t = 0; t < 4; ++t) {
            short4v pk;
            #pragma unroll
            for (int r = 0; r < 4; ++r) pk[r] = (short)pb[4 * t + r];
            *(short4v*)&P_lds[(r16 * 64 + 16 * t + 4 * g) ^ swz] = pk;
        }
        // --- O^T += V^T * P^T : 2 kpos chunks x 8 d-tiles
        #pragma unroll
        for (int c = 0; c < 2; ++c) {
            short8 pf = *(const short8*)&P_lds[(r16 * 64 + 32 * c + 8 * g) ^ swz];
            const ushort* vcol = Vt + (size_t)r16 * N_TOK + kv + 32 * c + 8 * g;
            #pragma unroll
            for (int dt = 0; dt < 8; ++dt) {
                short8 vf = *(const short8*)(vcol + (size_t)(16 * dt) * N_TOK);
                o[dt] = __builtin_amdgcn_mfma_f32_16x16x32_bf16(vf, pf, o[dt], 0, 0, 0);
            }
        }
    }
    // --- epilogue: partial O (pre-division) + (m, l)
    float* obase = Op + ((size_t)sp * N_TOK + qbase + r16) * D + 4 * g;
    #pragma unroll
    for (int dt = 0; dt < 8; ++dt) *(f32x4*)(obase + 16 * dt) = o[dt];
    if (g == 0) {
        float* ml = ML + ((size_t)sp * QTILES + qt) * 32;
        ml[r16] = m;
        ml[16 + r16] = l;
    }
}

// -------- kernel 4: merge the NS KV-split partials ---------------------------
template<int NS>
__global__ void merge_kernel(const float* __restrict__ Op, const float* __restrict__ ML,
                             float* __restrict__ out) {
    int i = blockIdx.x * blockDim.x + threadIdx.x;
    int e = i * 4;
    if (e >= N_TOK * D) return;
    int q = e >> 7;
    int qt = q >> 4, qr = q & 15;
    float mv[NS], lv[NS];
    float M = -INFINITY;
    #pragma unroll
    for (int s = 0; s < NS; ++s) {
        const float* ml = ML + ((size_t)s * QTILES + qt) * 32;
        mv[s] = ml[qr];
        lv[s] = ml[16 + qr];
        M = fmaxf(M, mv[s]);
    }
    float L = 0.f, a[NS];
    #pragma unroll
    for (int s = 0; s < NS; ++s) { a[s] = __expf(mv[s] - M); L += a[s] * lv[s]; }
    float inv = 1.f / L;
    f32x4 acc = zero4();
    #pragma unroll
    for (int s = 0; s < NS; ++s) {
        f32x4 ov = *(const f32x4*)(Op + (size_t)s * N_TOK * D + e);
        acc += ov * a[s];
    }
    *(f32x4*)(out + e) = acc * inv;
}

extern "C" void kernel_launch(void* const* d_in, const int* in_sizes, int n_in,
                              void* d_out, int out_size, void* d_ws, size_t ws_size,
                              hipStream_t stream) {
    const float* X  = (const float*)d_in[0];
    const float* Wq = (const float*)d_in[1];
    const float* Wk = (const float*)d_in[2];
    const float* Wv = (const float*)d_in[3];
    float* out = (float*)d_out;

    char* ws = (char*)d_ws;
    ushort* Xhi = (ushort*)(ws);                   // 2 MB
    ushort* Xlo = (ushort*)(ws + 2097152);         // 2 MB
    ushort* Whi = (ushort*)(ws + 4194304);         // 96 KB
    ushort* Wlo = (ushort*)(ws + 4292608);         // 96 KB
    ushort* Qhi = (ushort*)(ws + 4390912);         // 2 MB
    ushort* Qlo = (ushort*)(ws + 6488064);         // 2 MB
    ushort* Khi = (ushort*)(ws + 8585216);         // 2 MB
    ushort* Klo = (ushort*)(ws + 10682368);        // 2 MB
    ushort* Vt  = (ushort*)(ws + 12779520);        // 2 MB (transposed V)
    float*  Op  = (float*) (ws + 14876672);        // NS * 4 MB (split partials)

    const size_t op_off = 14876672;
    const size_t need8 = op_off + (size_t)8 * N_TOK * D * 4 + (size_t)8 * QTILES * 32 * 4;

    int nX = N_TOK * D;
    int total4 = (nX + 3 * 16384) / 4;
    cvt_kernel<<<(total4 + 255) / 256, 256, 0, stream>>>(X, Wq, Wk, Wv, Xhi, Xlo, Whi, Wlo, nX);
    proj_kernel<<<QTILES, 64, 0, stream>>>(Xhi, Xlo, Whi, Wlo, Qhi, Qlo, Khi, Klo, Vt);

    if (ws_size >= need8) {
        float* ML = (float*)(ws + op_off + (size_t)8 * N_TOK * D * 4);
        flash_kernel<8><<<QTILES * 8, 64, 0, stream>>>(Qhi, Qlo, Khi, Klo, Vt, Op, ML);
        merge_kernel<8><<<(N_TOK * D / 4 + 255) / 256, 256, 0, stream>>>(Op, ML, out);
    } else {
        float* ML = (float*)(ws + op_off + (size_t)4 * N_TOK * D * 4);
        flash_kernel<4><<<QTILES * 4, 64, 0, stream>>>(Qhi, Qlo, Khi, Klo, Vt, Op, ML);
        merge_kernel<4><<<(N_TOK * D / 4 + 255) / 256, 256, 0, stream>>>(Op, ML, out);
    }
}

// Round 4
// 168.959 us; speedup vs baseline: 2.3231x; 2.3231x over previous
//
#include <hip/hip_runtime.h>
#include <hip/hip_bf16.h>
#include <stdint.h>

#define N_TOK 8192
#define D 128
#define QTILES (N_TOK / 16)  // 512
#define KVB 64               // kv rows per staged tile

typedef __attribute__((ext_vector_type(8))) short short8;   // bf16x8 MFMA frag
typedef __attribute__((ext_vector_type(4))) short short4v;  // 4 bf16 (8B store)
typedef __attribute__((ext_vector_type(4))) float f32x4;    // MFMA accum

__device__ __forceinline__ ushort f2bf(float f) {
    union { float f; uint32_t u; } cv; cv.f = f;
    uint32_t u = cv.u;
    return (ushort)((u + 0x7fffu + ((u >> 16) & 1u)) >> 16);  // RNE
}
__device__ __forceinline__ float bf2f(ushort h) {
    union { uint32_t u; float f; } cv; cv.u = ((uint32_t)h) << 16;
    return cv.f;
}
__device__ __forceinline__ f32x4 zero4() {
    f32x4 z; z[0] = 0.f; z[1] = 0.f; z[2] = 0.f; z[3] = 0.f; return z;
}

// -------- kernel 1: f32 -> double-bf16 split (X and the 3 weights) ----------
__global__ void cvt_kernel(const float* __restrict__ X, const float* __restrict__ Wq,
                           const float* __restrict__ Wk, const float* __restrict__ Wv,
                           ushort* __restrict__ Xhi, ushort* __restrict__ Xlo,
                           ushort* __restrict__ Whi, ushort* __restrict__ Wlo, int nX) {
    int i = blockIdx.x * blockDim.x + threadIdx.x;
    int e = i * 4;
    int total = nX + 3 * 16384;
    if (e >= total) return;
    const float* src; ushort* dhi; ushort* dlo; int off;
    if (e < nX) { src = X; dhi = Xhi; dlo = Xlo; off = e; }
    else {
        int w = e - nX;
        int m = w >> 14;
        off = w & 16383;
        src = (m == 0) ? Wq : ((m == 1) ? Wk : Wv);
        dhi = Whi + (m << 14);
        dlo = Wlo + (m << 14);
    }
    f32x4 v = *(const f32x4*)(src + off);
    short4v ph, pl;
    #pragma unroll
    for (int r = 0; r < 4; ++r) {
        ushort h = f2bf(v[r]);
        ph[r] = (short)h;
        pl[r] = (short)f2bf(v[r] - bf2f(h));
    }
    *(short4v*)(dhi + off) = ph;
    *(short4v*)(dlo + off) = pl;
}

// -------- kernel 2: projections via MFMA (double-bf16 inputs) ---------------
__global__ __launch_bounds__(64) void proj_kernel(
    const ushort* __restrict__ Xhi, const ushort* __restrict__ Xlo,
    const ushort* __restrict__ Whi, const ushort* __restrict__ Wlo,
    ushort* __restrict__ Qhi, ushort* __restrict__ Qlo,
    ushort* __restrict__ Khi, ushort* __restrict__ Klo, ushort* __restrict__ Vt) {
    const int lane = threadIdx.x & 63;
    const int g = lane >> 4, r16 = lane & 15;
    const int nbase = blockIdx.x * 16;

    short8 xh[4], xl[4];
    const ushort* xrh = Xhi + (size_t)(nbase + r16) * D + 8 * g;
    const ushort* xrl = Xlo + (size_t)(nbase + r16) * D + 8 * g;
    #pragma unroll
    for (int ds = 0; ds < 4; ++ds) {
        xh[ds] = *(const short8*)(xrh + 32 * ds);
        xl[ds] = *(const short8*)(xrl + 32 * ds);
    }

    #pragma unroll
    for (int m = 0; m < 2; ++m) {
        const ushort* Wh = Whi + m * 16384;
        const ushort* Wl = Wlo + m * 16384;
        ushort* Oh = m ? Khi : Qhi;
        ushort* Ol = m ? Klo : Qlo;
        #pragma unroll
        for (int jt = 0; jt < 8; ++jt) {
            f32x4 acc = zero4();
            const ushort* wrh = Wh + (size_t)(16 * jt + r16) * D + 8 * g;
            const ushort* wrl = Wl + (size_t)(16 * jt + r16) * D + 8 * g;
            #pragma unroll
            for (int ds = 0; ds < 4; ++ds) {
                short8 wh = *(const short8*)(wrh + 32 * ds);
                short8 wl = *(const short8*)(wrl + 32 * ds);
                acc = __builtin_amdgcn_mfma_f32_16x16x32_bf16(wh, xh[ds], acc, 0, 0, 0);
                acc = __builtin_amdgcn_mfma_f32_16x16x32_bf16(wh, xl[ds], acc, 0, 0, 0);
                acc = __builtin_amdgcn_mfma_f32_16x16x32_bf16(wl, xh[ds], acc, 0, 0, 0);
            }
            short4v ph, pl;
            #pragma unroll
            for (int r = 0; r < 4; ++r) {
                ushort h = f2bf(acc[r]);
                ph[r] = (short)h;
                pl[r] = (short)f2bf(acc[r] - bf2f(h));
            }
            size_t oo = (size_t)(nbase + r16) * D + 16 * jt + 4 * g;
            *(short4v*)(Oh + oo) = ph;
            *(short4v*)(Ol + oo) = pl;
        }
    }
    {
        const ushort* Wh = Whi + 32768;
        const ushort* Wl = Wlo + 32768;
        #pragma unroll
        for (int jt = 0; jt < 8; ++jt) {
            f32x4 acc = zero4();
            const ushort* wrh = Wh + (size_t)(16 * jt + r16) * D + 8 * g;
            const ushort* wrl = Wl + (size_t)(16 * jt + r16) * D + 8 * g;
            #pragma unroll
            for (int ds = 0; ds < 4; ++ds) {
                short8 wh = *(const short8*)(wrh + 32 * ds);
                short8 wl = *(const short8*)(wrl + 32 * ds);
                acc = __builtin_amdgcn_mfma_f32_16x16x32_bf16(xh[ds], wh, acc, 0, 0, 0);
                acc = __builtin_amdgcn_mfma_f32_16x16x32_bf16(xl[ds], wh, acc, 0, 0, 0);
                acc = __builtin_amdgcn_mfma_f32_16x16x32_bf16(xh[ds], wl, acc, 0, 0, 0);
            }
            short4v pk;
            #pragma unroll
            for (int r = 0; r < 4; ++r) pk[r] = (short)f2bf(acc[r]);
            *(short4v*)(Vt + (size_t)(16 * jt + r16) * N_TOK + nbase + 4 * g) = pk;
        }
    }
}

// -------- kernel 3: flash attention, LDS-staged, 4 waves / 128 q-rows -------
// Each wave computes 32 q-rows (2 x 16 subtiles). K/V tiles staged to LDS by
// the whole block; fragment reads are swizzled ds_read_b128 (bank-even).
// S^T = K*Q^T in double-bf16 -> q = lane&15 lane-local softmax.
// O^T = V^T*P^T -> lane-local rescale; float4 epilogue.
template<int NS>
__global__ __launch_bounds__(256, 2) void flash_kernel(
    const ushort* __restrict__ Qhi, const ushort* __restrict__ Qlo,
    const ushort* __restrict__ Khi, const ushort* __restrict__ Klo,
    const ushort* __restrict__ Vt, float* __restrict__ Op, float* __restrict__ ML) {
    __shared__ __align__(16) ushort Kh_lds[KVB * D];   // 16 KB, swizzled
    __shared__ __align__(16) ushort Kl_lds[KVB * D];   // 16 KB, swizzled
    __shared__ __align__(16) ushort V_lds[D * KVB];    // 16 KB, d-major, swizzled
    __shared__ __align__(16) ushort P_lds[4 * 2048];   // 4 KB per wave

    const int tid = threadIdx.x;
    const int lane = tid & 63;
    const int wid = tid >> 6;
    const int g = lane >> 4, r16 = lane & 15;
    const int sp = blockIdx.x % NS;        // XCD-affine split
    const int qg = blockIdx.x / NS;        // [0, N_TOK/128)
    const int kv0 = sp * (N_TOK / NS);
    const int nIter = (N_TOK / NS) / KVB;
    const int qbase = qg * 128 + wid * 32;

    // ---- hoist Q fragments (2 subtiles x 4 d-slices, hi+lo)
    short8 qh[2][4], ql[2][4];
    #pragma unroll
    for (int qa = 0; qa < 2; ++qa) {
        const ushort* qrh = Qhi + (size_t)(qbase + 16 * qa + r16) * D + 8 * g;
        const ushort* qrl = Qlo + (size_t)(qbase + 16 * qa + r16) * D + 8 * g;
        #pragma unroll
        for (int ds = 0; ds < 4; ++ds) {
            qh[qa][ds] = *(const short8*)(qrh + 32 * ds);
            ql[qa][ds] = *(const short8*)(qrl + 32 * ds);
        }
    }

    float m[2] = {-INFINITY, -INFINITY}, l[2] = {0.f, 0.f};
    f32x4 o[2][8];
    #pragma unroll
    for (int qa = 0; qa < 2; ++qa)
        #pragma unroll
        for (int dt = 0; dt < 8; ++dt) o[qa][dt] = zero4();

    ushort* P_w = &P_lds[wid * 2048];

    for (int it = 0; it < nIter; ++it) {
        const int kv = kv0 + it * KVB;
        __syncthreads();   // previous compute done before overwriting LDS
        // ---- stage K (hi+lo): 64 rows x 256B, 16B per thread-slot
        #pragma unroll
        for (int rr = 0; rr < 4; ++rr) {
            int idx = tid + 256 * rr;          // [0,1024)
            int row = idx >> 4, seg = idx & 15;
            short8 v1 = *(const short8*)(Khi + (size_t)(kv + row) * D + seg * 8);
            short8 v2 = *(const short8*)(Klo + (size_t)(kv + row) * D + seg * 8);
            int el = (row * 128 + seg * 8) ^ ((row & 7) << 3);
            *(short8*)&Kh_lds[el] = v1;
            *(short8*)&Kl_lds[el] = v2;
        }
        // ---- stage V^T slice: 128 d-rows x 128B
        #pragma unroll
        for (int rr = 0; rr < 4; ++rr) {
            int idx = tid + 256 * rr;          // [0,1024)
            int row = idx >> 3, seg = idx & 7;
            short8 v = *(const short8*)(Vt + (size_t)row * N_TOK + kv + seg * 8);
            int el = (row * 64 + seg * 8) ^ ((row & 7) << 3);
            *(short8*)&V_lds[el] = v;
        }
        __syncthreads();

        // ---- S^T = K*Q^T : 4 kv-subtiles x 4 d-slices x 3 split terms x 2 qa
        f32x4 s[2][4];
        #pragma unroll
        for (int qa = 0; qa < 2; ++qa)
            #pragma unroll
            for (int t = 0; t < 4; ++t) s[qa][t] = zero4();
        #pragma unroll
        for (int t = 0; t < 4; ++t) {
            #pragma unroll
            for (int ds = 0; ds < 4; ++ds) {
                int row = 16 * t + r16;
                int el = (row * 128 + 32 * ds + 8 * g) ^ ((row & 7) << 3);
                short8 kh = *(const short8*)&Kh_lds[el];
                short8 kl = *(const short8*)&Kl_lds[el];
                #pragma unroll
                for (int qa = 0; qa < 2; ++qa) {
                    s[qa][t] = __builtin_amdgcn_mfma_f32_16x16x32_bf16(kh, qh[qa][ds], s[qa][t], 0, 0, 0);
                    s[qa][t] = __builtin_amdgcn_mfma_f32_16x16x32_bf16(kh, ql[qa][ds], s[qa][t], 0, 0, 0);
                    s[qa][t] = __builtin_amdgcn_mfma_f32_16x16x32_bf16(kl, qh[qa][ds], s[qa][t], 0, 0, 0);
                }
            }
        }
        // ---- online softmax per q-subtile (lane-local per r16)
        #pragma unroll
        for (int qa = 0; qa < 2; ++qa) {
            float tm = -INFINITY;
            #pragma unroll
            for (int t = 0; t < 4; ++t)
                #pragma unroll
                for (int r = 0; r < 4; ++r) tm = fmaxf(tm, s[qa][t][r]);
            tm = fmaxf(tm, __shfl_xor(tm, 16));
            tm = fmaxf(tm, __shfl_xor(tm, 32));
            float mnew = fmaxf(m[qa], tm);
            float scale = __expf(m[qa] - mnew);
            float psum = 0.f;
            #pragma unroll
            for (int t = 0; t < 4; ++t) {
                short4v pk;
                #pragma unroll
                for (int r = 0; r < 4; ++r) {
                    float p = __expf(s[qa][t][r] - mnew);
                    psum += p;
                    pk[r] = (short)f2bf(p);
                }
                *(short4v*)&P_w[(qa * 1024 + r16 * 64 + 16 * t + 4 * g) ^ ((r16 & 7) << 3)] = pk;
            }
            psum += __shfl_xor(psum, 16);
            psum += __shfl_xor(psum, 32);
            l[qa] = l[qa] * scale + psum;
            m[qa] = mnew;
            #pragma unroll
            for (int dt = 0; dt < 8; ++dt) o[qa][dt] *= scale;
        }
        // ---- O^T += V^T * P^T : 2 kv-chunks x 8 d-tiles, V frag shared by qa
        #pragma unroll
        for (int c = 0; c < 2; ++c) {
            short8 pf0 = *(const short8*)&P_w[(r16 * 64 + 32 * c + 8 * g) ^ ((r16 & 7) << 3)];
            short8 pf1 = *(const short8*)&P_w[(1024 + r16 * 64 + 32 * c + 8 * g) ^ ((r16 & 7) << 3)];
            #pragma unroll
            for (int dt = 0; dt < 8; ++dt) {
                int row = 16 * dt + r16;
                int el = (row * 64 + 32 * c + 8 * g) ^ ((row & 7) << 3);
                short8 vf = *(const short8*)&V_lds[el];
                o[0][dt] = __builtin_amdgcn_mfma_f32_16x16x32_bf16(vf, pf0, o[0][dt], 0, 0, 0);
                o[1][dt] = __builtin_amdgcn_mfma_f32_16x16x32_bf16(vf, pf1, o[1][dt], 0, 0, 0);
            }
        }
    }
    // ---- epilogue: partial O (pre-division) + (m, l)
    #pragma unroll
    for (int qa = 0; qa < 2; ++qa) {
        float* obase = Op + ((size_t)sp * N_TOK + qbase + 16 * qa + r16) * D + 4 * g;
        #pragma unroll
        for (int dt = 0; dt < 8; ++dt) *(f32x4*)(obase + 16 * dt) = o[qa][dt];
        if (g == 0) {
            int qt = (qbase + 16 * qa) >> 4;
            float* ml = ML + ((size_t)sp * QTILES + qt) * 32;
            ml[r16] = m[qa];
            ml[16 + r16] = l[qa];
        }
    }
}

// -------- kernel 4: merge the NS KV-split partials ---------------------------
template<int NS>
__global__ void merge_kernel(const float* __restrict__ Op, const float* __restrict__ ML,
                             float* __restrict__ out) {
    int i = blockIdx.x * blockDim.x + threadIdx.x;
    int e = i * 4;
    if (e >= N_TOK * D) return;
    int q = e >> 7;
    int qt = q >> 4, qr = q & 15;
    float mv[NS], lv[NS];
    float M = -INFINITY;
    #pragma unroll
    for (int s = 0; s < NS; ++s) {
        const float* ml = ML + ((size_t)s * QTILES + qt) * 32;
        mv[s] = ml[qr];
        lv[s] = ml[16 + qr];
        M = fmaxf(M, mv[s]);
    }
    float L = 0.f, a[NS];
    #pragma unroll
    for (int s = 0; s < NS; ++s) { a[s] = __expf(mv[s] - M); L += a[s] * lv[s]; }
    float inv = 1.f / L;
    f32x4 acc = zero4();
    #pragma unroll
    for (int s = 0; s < NS; ++s) {
        f32x4 ov = *(const f32x4*)(Op + (size_t)s * N_TOK * D + e);
        acc += ov * a[s];
    }
    *(f32x4*)(out + e) = acc * inv;
}

extern "C" void kernel_launch(void* const* d_in, const int* in_sizes, int n_in,
                              void* d_out, int out_size, void* d_ws, size_t ws_size,
                              hipStream_t stream) {
    const float* X  = (const float*)d_in[0];
    const float* Wq = (const float*)d_in[1];
    const float* Wk = (const float*)d_in[2];
    const float* Wv = (const float*)d_in[3];
    float* out = (float*)d_out;

    char* ws = (char*)d_ws;
    ushort* Xhi = (ushort*)(ws);                   // 2 MB
    ushort* Xlo = (ushort*)(ws + 2097152);         // 2 MB
    ushort* Whi = (ushort*)(ws + 4194304);         // 96 KB
    ushort* Wlo = (ushort*)(ws + 4292608);         // 96 KB
    ushort* Qhi = (ushort*)(ws + 4390912);         // 2 MB
    ushort* Qlo = (ushort*)(ws + 6488064);         // 2 MB
    ushort* Khi = (ushort*)(ws + 8585216);         // 2 MB
    ushort* Klo = (ushort*)(ws + 10682368);        // 2 MB
    ushort* Vt  = (ushort*)(ws + 12779520);        // 2 MB (transposed V)
    float*  Op  = (float*) (ws + 14876672);        // NS * 4 MB (split partials)

    const size_t op_off = 14876672;
    const size_t need8 = op_off + (size_t)8 * N_TOK * D * 4 + (size_t)8 * QTILES * 32 * 4;

    int nX = N_TOK * D;
    int total4 = (nX + 3 * 16384) / 4;
    cvt_kernel<<<(total4 + 255) / 256, 256, 0, stream>>>(X, Wq, Wk, Wv, Xhi, Xlo, Whi, Wlo, nX);
    proj_kernel<<<QTILES, 64, 0, stream>>>(Xhi, Xlo, Whi, Wlo, Qhi, Qlo, Khi, Klo, Vt);

    if (ws_size >= need8) {
        float* ML = (float*)(ws + op_off + (size_t)8 * N_TOK * D * 4);
        flash_kernel<8><<<(N_TOK / 128) * 8, 256, 0, stream>>>(Qhi, Qlo, Khi, Klo, Vt, Op, ML);
        merge_kernel<8><<<(N_TOK * D / 4 + 255) / 256, 256, 0, stream>>>(Op, ML, out);
    } else {
        float* ML = (float*)(ws + op_off + (size_t)4 * N_TOK * D * 4);
        flash_kernel<4><<<(N_TOK / 128) * 4, 256, 0, stream>>>(Qhi, Qlo, Khi, Klo, Vt, Op, ML);
        merge_kernel<4><<<(N_TOK * D / 4 + 255) / 256, 256, 0, stream>>>(Op, ML, out);
    }
}